// Round 13
// baseline (33258.194 us; speedup 1.0000x reference)
//
#include <hip/hip_runtime.h>

#define BB 16
#define SS 128
#define TT 128
#define EE 512
#define HH 512
#define DD 1024
#define VO 10000

typedef _Float16 half4_t __attribute__((ext_vector_type(4)));
typedef _Float16 half8_t __attribute__((ext_vector_type(8)));

#define FMA4(A, W, X)              \
  A = fmaf((W).x, (X).x, A);       \
  A = fmaf((W).y, (X).y, A);       \
  A = fmaf((W).z, (X).z, A);       \
  A = fmaf((W).w, (X).w, A)

__device__ __forceinline__ float4 h2f4(half4_t h) {
  return make_float4((float)h[0], (float)h[1], (float)h[2], (float)h[3]);
}

__device__ __forceinline__ float wred(float s) {
#pragma unroll
  for (int off = 32; off >= 1; off >>= 1) s += __shfl_xor(s, off, 64);
  return s;
}
__device__ __forceinline__ float sigm(float x) { return 1.f / (1.f + expf(-x)); }

__device__ __forceinline__ void stv(float* p, float v) {
  __hip_atomic_store(p, v, __ATOMIC_RELAXED, __HIP_MEMORY_SCOPE_AGENT);
}

// ---- grid barrier v2: flag-scan, relaxed-only (validated R7-R12) ----
__device__ __forceinline__ void gbar2(unsigned* bar, int lb, int nblk, unsigned target) {
  asm volatile("s_waitcnt vmcnt(0) lgkmcnt(0)" ::: "memory");
  __syncthreads();
  if (threadIdx.x == 0)
    __hip_atomic_store(bar + lb * 16, target, __ATOMIC_RELAXED, __HIP_MEMORY_SCOPE_AGENT);
  if (lb == 0) {
    for (int i = threadIdx.x; i < nblk; i += blockDim.x)
      while (__hip_atomic_load(bar + i * 16, __ATOMIC_RELAXED, __HIP_MEMORY_SCOPE_AGENT) <
             target)
        __builtin_amdgcn_s_sleep(1);
    __syncthreads();
    if (threadIdx.x == 0)
      __hip_atomic_store(bar + 8192, target, __ATOMIC_RELAXED, __HIP_MEMORY_SCOPE_AGENT);
  }
  if (threadIdx.x == 0)
    while (__hip_atomic_load(bar + 8192, __ATOMIC_RELAXED, __HIP_MEMORY_SCOPE_AGENT) <
           target)
      __builtin_amdgcn_s_sleep(1);
  __syncthreads();
}

// ---- fp32 -> fp16 conversion (8 elems/thread) ----
__global__ void f2h_k(const float* __restrict__ src, _Float16* __restrict__ dst, int n8) {
  const int i = blockIdx.x * blockDim.x + threadIdx.x;
  if (i < n8) {
    const float4 a = *(const float4*)&src[i * 8];
    const float4 b = *(const float4*)&src[i * 8 + 4];
    half8_t h;
    h[0] = a.x; h[1] = a.y; h[2] = a.z; h[3] = a.w;
    h[4] = b.x; h[5] = b.y; h[6] = b.z; h[7] = b.w;
    *(half8_t*)&dst[i * 8] = h;
  }
}

// ---- embedding gather (padding_idx=0 -> zeros), out layout [Sn][B][E] ----
__global__ void gather_k(const int* __restrict__ idx, const float* __restrict__ emb,
                         float* __restrict__ out, int Sn) {
  const int s = blockIdx.x, b = blockIdx.y, tid = threadIdx.x;
  const int id = idx[b * Sn + s];
  float4 v = make_float4(0.f, 0.f, 0.f, 0.f);
  if (id != 0) v = ((const float4*)(emb + (size_t)id * EE))[tid];
  ((float4*)(out + ((size_t)s * BB + b) * EE))[tid] = v;
}

// ---- G[z][n][m] = sum_k X[m,k]*W[z,n,k]; mg loop INSIDE so the 4 W rows a
// block needs stay L1-resident instead of being re-fetched per m-group ----
template <int K>
__global__ void gemv16c_k(const float* __restrict__ X, int ldx,
                          const float* __restrict__ W, int ldw,
                          float* __restrict__ G, int M, size_t wz, size_t gz) {
  const int lane = threadIdx.x & 63;
  const int n = blockIdx.x * 4 + (threadIdx.x >> 6);
  const int z = blockIdx.y;
  const float* Wn = W + (size_t)z * wz + (size_t)n * ldw;
#pragma unroll 1
  for (int mg = 0; mg < M / 16; ++mg) {
    const float* Xr = X + (size_t)mg * 16 * ldx;
    float acc[16];
#pragma unroll
    for (int j = 0; j < 16; ++j) acc[j] = 0.f;
#pragma unroll
    for (int it = 0; it < K / 256; ++it) {
      const int k = it * 256 + lane * 4;
      const float4 w4 = *(const float4*)&Wn[k];
#pragma unroll
      for (int j = 0; j < 16; ++j) {
        const float4 xv = *(const float4*)&Xr[(size_t)j * ldx + k];
        FMA4(acc[j], w4, xv);
      }
    }
#pragma unroll
    for (int j = 0; j < 16; ++j) acc[j] = wred(acc[j]);
    float sel = 0.f;
#pragma unroll
    for (int j = 0; j < 16; ++j)
      if (lane == j) sel = acc[j];
    if (lane < 16) G[(size_t)z * gz + (size_t)n * M + mg * 16 + lane] = sel;
  }
}

// ---- persistent encoder: 256 blocks x 512 thr (unchanged from R9/R12) ----
__global__ __launch_bounds__(512, 4) void enc_mega7_k(
    const float* __restrict__ gx, const float* __restrict__ whh,
    const float* __restrict__ bias, float* __restrict__ h_all,
    float* __restrict__ seq, int seq_ts, int seq_bs, unsigned* __restrict__ barbase) {
  const int tid = threadIdx.x, lane = tid & 63, lw = tid >> 6;
  const int dir = blockIdx.x >> 7;
  const int lb = blockIdx.x & 127;
  const int w2 = lb * 8 + lw;
  const int d = w2 >> 1, bq = w2 & 1;
  unsigned* bar = barbase + dir * 16384;

  __shared__ float hs[16][512];

  float wr[4][8];
  const float* wsrc = whh + (size_t)dir * (4 * HH * HH);
#pragma unroll
  for (int g = 0; g < 4; ++g)
#pragma unroll
    for (int j = 0; j < 8; ++j)
      wr[g][j] = wsrc[(size_t)(g * HH + d) * HH + j * 64 + lane];
  float bv[4];
#pragma unroll
  for (int g = 0; g < 4; ++g) bv[g] = bias[dir * 4 * HH + g * HH + d];
  const float* gxz = gx + (size_t)dir * ((size_t)4 * HH * 2048);
  float creg = 0.f;
  unsigned bt = 0;

  for (int t = 0; t < SS; ++t) {
    const int idx = dir ? (SS - 1 - t) : t;
    const float* hp = h_all + ((size_t)t * 2 + dir) * (BB * HH);
    for (int i = tid; i < BB * HH / 4; i += 512)
      *(float4*)&((float*)hs)[i * 4] = *(const float4*)&hp[i * 4];
    __syncthreads();
    float acc[4][8];
#pragma unroll
    for (int g = 0; g < 4; ++g)
#pragma unroll
      for (int j = 0; j < 8; ++j) acc[g][j] = 0.f;
#pragma unroll
    for (int kb = 0; kb < 8; ++kb) {
      const int k = kb * 64 + lane;
#pragma unroll
      for (int j = 0; j < 8; ++j) {
        const float xv = hs[bq * 8 + j][k];
#pragma unroll
        for (int g = 0; g < 4; ++g) acc[g][j] = fmaf(wr[g][kb], xv, acc[g][j]);
      }
    }
#pragma unroll
    for (int g = 0; g < 4; ++g)
#pragma unroll
      for (int j = 0; j < 8; ++j) acc[g][j] = wred(acc[g][j]);
    float s0 = 0.f, s1 = 0.f, s2 = 0.f, s3 = 0.f;
#pragma unroll
    for (int j = 0; j < 8; ++j)
      if (lane == j) { s0 = acc[0][j]; s1 = acc[1][j]; s2 = acc[2][j]; s3 = acc[3][j]; }
    if (lane < 8) {
      const int b = bq * 8 + lane;
      const int m = idx * 16 + b;
      const float gi = sigm(s0 + bv[0] + gxz[(size_t)(0 * HH + d) * 2048 + m]);
      const float gf = sigm(s1 + bv[1] + gxz[(size_t)(1 * HH + d) * 2048 + m]);
      const float gg = tanhf(s2 + bv[2] + gxz[(size_t)(2 * HH + d) * 2048 + m]);
      const float go = sigm(s3 + bv[3] + gxz[(size_t)(3 * HH + d) * 2048 + m]);
      const float cn = gf * creg + gi * gg;
      creg = cn;
      const float hv = go * tanhf(cn);
      stv(h_all + ((size_t)(t + 1) * 2 + dir) * (BB * HH) + b * HH + d, hv);
      seq[(size_t)idx * seq_ts + (size_t)b * seq_bs + dir * HH + d] = hv;
    }
    gbar2(bar, lb, 128, ++bt);
  }
}

// ---- persistent decoder vA: 512 blocks x 1024 thr (2 blocks/CU -> 100% occ),
// fp16 weights; wave = (d, batch-PAIR) owns all 4 gate rows; 5 barriers/step ----
__global__ __launch_bounds__(1024, 8) void dec_megaA_k(
    const float* __restrict__ gs_emb, const float* __restrict__ encWe,
    const float* __restrict__ enc_out, const _Float16* __restrict__ aw16,
    const float* __restrict__ attn_b, const float* __restrict__ attn_v,
    const _Float16* __restrict__ w16i0, const _Float16* __restrict__ w16h0,
    const float* __restrict__ b0, const _Float16* __restrict__ w16i1,
    const _Float16* __restrict__ w16h1, const float* __restrict__ b1,
    const float* __restrict__ zeros, float* __restrict__ h0_all,
    float* __restrict__ h1_all, float* __restrict__ c1_all, float* __restrict__ wtd_all,
    float* __restrict__ qW_all, float* __restrict__ scores_all,
    unsigned* __restrict__ bar) {
  const int tid = threadIdx.x, lane = tid & 63, lw = tid >> 6;
  const int blk = blockIdx.x;     // 0..511
  const int dl = lw >> 3;         // 0..1: which d of this block
  const int d = blk * 2 + dl;     // 0..1023
  const int bp = lw & 7;          // batch pair: batches bp*2, bp*2+1
  const int b_att = blk >> 5, shard = blk & 31;

  __shared__ float sco[SS];
  __shared__ float sred[32][33];

  const _Float16* w0i0 = w16i0 + (size_t)(0 * DD + d) * 1536;
  const _Float16* w0i1 = w16i0 + (size_t)(1 * DD + d) * 1536;
  const _Float16* w0i2 = w16i0 + (size_t)(2 * DD + d) * 1536;
  const _Float16* w0i3 = w16i0 + (size_t)(3 * DD + d) * 1536;
  const _Float16* w0h0 = w16h0 + (size_t)(0 * DD + d) * 1024;
  const _Float16* w0h1 = w16h0 + (size_t)(1 * DD + d) * 1024;
  const _Float16* w0h2 = w16h0 + (size_t)(2 * DD + d) * 1024;
  const _Float16* w0h3 = w16h0 + (size_t)(3 * DD + d) * 1024;
  const _Float16* w1i0 = w16i1 + (size_t)(0 * DD + d) * 1024;
  const _Float16* w1i1 = w16i1 + (size_t)(1 * DD + d) * 1024;
  const _Float16* w1i2 = w16i1 + (size_t)(2 * DD + d) * 1024;
  const _Float16* w1i3 = w16i1 + (size_t)(3 * DD + d) * 1024;
  const _Float16* w1h0 = w16h1 + (size_t)(0 * DD + d) * 1024;
  const _Float16* w1h1 = w16h1 + (size_t)(1 * DD + d) * 1024;
  const _Float16* w1h2 = w16h1 + (size_t)(2 * DD + d) * 1024;
  const _Float16* w1h3 = w16h1 + (size_t)(3 * DD + d) * 1024;
  float bv0[4], bv1[4];
#pragma unroll
  for (int g = 0; g < 4; ++g) { bv0[g] = b0[g * DD + d]; bv1[g] = b1[g * DD + d]; }
  const float abv = attn_b[d];
  float c0 = 0.f, c1 = 0.f;
  unsigned bt = 0;

  // ---- prime layer 0: every wave initializes c0 for its own batches ----
  {
    const float cn = sigm(bv0[0]) * tanhf(bv0[2]);
    c0 = cn;  // input & state are zero -> same c0 for every batch
    if (lane < 2) stv(h0_all + (bp * 2 + lane) * DD + d, sigm(bv0[3]) * tanhf(cn));
  }
  gbar2(bar, blk, 512, ++bt);
  // ---- prime layer 1: w1i . h0_all[0]  (h1prev = 0); every wave, own batches ----
  {
    float acc[4][2];
#pragma unroll
    for (int g = 0; g < 4; ++g) { acc[g][0] = 0.f; acc[g][1] = 0.f; }
#pragma unroll
    for (int it = 0; it < 4; ++it) {
      const int k = it * 256 + lane * 4;
      const float4 q0 = h2f4(*(const half4_t*)&w1i0[k]);
      const float4 q1 = h2f4(*(const half4_t*)&w1i1[k]);
      const float4 q2 = h2f4(*(const half4_t*)&w1i2[k]);
      const float4 q3 = h2f4(*(const half4_t*)&w1i3[k]);
#pragma unroll
      for (int j = 0; j < 2; ++j) {
        const float4 xv = *(const float4*)&h0_all[(bp * 2 + j) * DD + k];
        FMA4(acc[0][j], q0, xv);
        FMA4(acc[1][j], q1, xv);
        FMA4(acc[2][j], q2, xv);
        FMA4(acc[3][j], q3, xv);
      }
    }
#pragma unroll
    for (int g = 0; g < 4; ++g) { acc[g][0] = wred(acc[g][0]); acc[g][1] = wred(acc[g][1]); }
    float s[4] = {0.f, 0.f, 0.f, 0.f};
#pragma unroll
    for (int j = 0; j < 2; ++j)
      if (lane == j) { s[0] = acc[0][j]; s[1] = acc[1][j]; s[2] = acc[2][j]; s[3] = acc[3][j]; }
    if (lane < 2) {
      const int b = bp * 2 + lane;
      const float cn = sigm(s[0] + bv1[0]) * tanhf(s[2] + bv1[2]);
      c1 = cn;
      stv(c1_all + b * DD + d, cn);
      stv(h1_all + b * DD + d, sigm(s[3] + bv1[3]) * tanhf(cn));
    }
  }
  gbar2(bar, blk, 512, ++bt);

  for (int t = 0; t < TT; ++t) {
    // ===== qW[b,d] = attn_b[d] + c1[b,:].attn_w[d,:1024]  (fp16 row) =====
    {
      const float* cb = c1_all + (size_t)t * (BB * DD);
      float qa[2] = {0.f, 0.f};
#pragma unroll
      for (int it = 0; it < 4; ++it) {
        const int k = it * 256 + lane * 4;
        const float4 w4 = h2f4(*(const half4_t*)&aw16[(size_t)d * 2048 + k]);
#pragma unroll
        for (int j = 0; j < 2; ++j) {
          const float4 xv = *(const float4*)&cb[(bp * 2 + j) * DD + k];
          FMA4(qa[j], w4, xv);
        }
      }
      qa[0] = wred(qa[0]);
      qa[1] = wred(qa[1]);
      float sel = 0.f;
      if (lane == 0) sel = qa[0];
      if (lane == 1) sel = qa[1];
      if (lane < 2)
        stv(qW_all + (size_t)t * (BB * DD) + (bp * 2 + lane) * DD + d, sel + abv);
    }
    gbar2(bar, blk, 512, ++bt);
    // ===== scores[b_att, shard*4 + lw] (lw < 4) =====
    if (lw < 4) {
      const int s = shard * 4 + lw;
      const float* ew = encWe + ((size_t)(b_att * SS + s)) * DD;
      const float* qb = qW_all + (size_t)t * (BB * DD) + b_att * DD;
      float a = 0.f;
#pragma unroll
      for (int it = 0; it < 4; ++it) {
        const int k = it * 256 + lane * 4;
        const float4 e4 = *(const float4*)&ew[k];
        const float4 q4 = *(const float4*)&qb[k];
        const float4 v4 = *(const float4*)&attn_v[k];
        a += v4.x * tanhf(q4.x + e4.x) + v4.y * tanhf(q4.y + e4.y) +
             v4.z * tanhf(q4.z + e4.z) + v4.w * tanhf(q4.w + e4.w);
      }
      a = wred(a);
      if (lane == 0) stv(scores_all + (size_t)t * (BB * SS) + b_att * SS + s, a);
    }
    gbar2(bar, blk, 512, ++bt);
    // ===== softmax + weighted: cols shard*32..+31 of batch b_att =====
    {
      if (tid < SS) sco[tid] = scores_all[(size_t)t * (BB * SS) + b_att * SS + tid];
      __syncthreads();
      float m = -1e30f;
      for (int s = 0; s < SS; ++s) m = fmaxf(m, sco[s]);
      __syncthreads();
      if (tid < SS) sco[tid] = expf(sco[tid] - m);
      __syncthreads();
      float sum = 0.f;
      for (int s = 0; s < SS; ++s) sum += sco[s];
      const float inv = 1.f / sum;
      const int col = tid & 31, sg = tid >> 5;  // 32 s-groups of 4
      float p = 0.f;
#pragma unroll
      for (int i = 0; i < 4; ++i) {
        const int s = sg * 4 + i;
        p += sco[s] * enc_out[((size_t)(b_att * SS + s)) * DD + shard * 32 + col];
      }
      sred[sg][col] = p;
      __syncthreads();
      if (tid < 32) {
        float a2 = 0.f;
#pragma unroll
        for (int i = 0; i < 32; ++i) a2 += sred[i][tid];
        stv(wtd_all + (size_t)t * (BB * DD) + b_att * DD + shard * 32 + tid, a2 * inv);
      }
    }
    gbar2(bar, blk, 512, ++bt);
    // ===== decoder layer 0: K = wtd(1024) | emb(512) | h0prev(1024) =====
    {
      const float* xw = wtd_all + (size_t)t * (BB * DD);
      const float* em = t ? gs_emb + (size_t)(t - 1) * (BB * EE) : zeros;
      const float* hp = h0_all + (size_t)t * (BB * DD);
      float acc[4][2];
#pragma unroll
      for (int g = 0; g < 4; ++g) { acc[g][0] = 0.f; acc[g][1] = 0.f; }
#pragma unroll
      for (int it = 0; it < 4; ++it) {
        const int k = it * 256 + lane * 4;
        const float4 q0 = h2f4(*(const half4_t*)&w0i0[k]);
        const float4 q1 = h2f4(*(const half4_t*)&w0i1[k]);
        const float4 q2 = h2f4(*(const half4_t*)&w0i2[k]);
        const float4 q3 = h2f4(*(const half4_t*)&w0i3[k]);
#pragma unroll
        for (int j = 0; j < 2; ++j) {
          const float4 xv = *(const float4*)&xw[(bp * 2 + j) * DD + k];
          FMA4(acc[0][j], q0, xv);
          FMA4(acc[1][j], q1, xv);
          FMA4(acc[2][j], q2, xv);
          FMA4(acc[3][j], q3, xv);
        }
      }
#pragma unroll
      for (int it = 4; it < 6; ++it) {
        const int k = it * 256 + lane * 4;
        const float4 q0 = h2f4(*(const half4_t*)&w0i0[k]);
        const float4 q1 = h2f4(*(const half4_t*)&w0i1[k]);
        const float4 q2 = h2f4(*(const half4_t*)&w0i2[k]);
        const float4 q3 = h2f4(*(const half4_t*)&w0i3[k]);
#pragma unroll
        for (int j = 0; j < 2; ++j) {
          const float4 xv = *(const float4*)&em[(bp * 2 + j) * EE + (k - 1024)];
          FMA4(acc[0][j], q0, xv);
          FMA4(acc[1][j], q1, xv);
          FMA4(acc[2][j], q2, xv);
          FMA4(acc[3][j], q3, xv);
        }
      }
#pragma unroll
      for (int it = 0; it < 4; ++it) {
        const int k = it * 256 + lane * 4;
        const float4 q0 = h2f4(*(const half4_t*)&w0h0[k]);
        const float4 q1 = h2f4(*(const half4_t*)&w0h1[k]);
        const float4 q2 = h2f4(*(const half4_t*)&w0h2[k]);
        const float4 q3 = h2f4(*(const half4_t*)&w0h3[k]);
#pragma unroll
        for (int j = 0; j < 2; ++j) {
          const float4 xv = *(const float4*)&hp[(bp * 2 + j) * DD + k];
          FMA4(acc[0][j], q0, xv);
          FMA4(acc[1][j], q1, xv);
          FMA4(acc[2][j], q2, xv);
          FMA4(acc[3][j], q3, xv);
        }
      }
#pragma unroll
      for (int g = 0; g < 4; ++g) { acc[g][0] = wred(acc[g][0]); acc[g][1] = wred(acc[g][1]); }
      float s[4] = {0.f, 0.f, 0.f, 0.f};
#pragma unroll
      for (int j = 0; j < 2; ++j)
        if (lane == j) { s[0] = acc[0][j]; s[1] = acc[1][j]; s[2] = acc[2][j]; s[3] = acc[3][j]; }
      if (lane < 2) {
        const int b = bp * 2 + lane;
        const float cn = sigm(s[1] + bv0[1]) * c0 + sigm(s[0] + bv0[0]) * tanhf(s[2] + bv0[2]);
        c0 = cn;
        stv(h0_all + (size_t)(t + 1) * (BB * DD) + b * DD + d,
            sigm(s[3] + bv0[3]) * tanhf(cn));
      }
    }
    gbar2(bar, blk, 512, ++bt);
    // ===== decoder layer 1: K = h0new(1024) | h1prev(1024) =====
    {
      const float* h0 = h0_all + (size_t)(t + 1) * (BB * DD);
      const float* h1p = h1_all + (size_t)t * (BB * DD);
      float acc[4][2];
#pragma unroll
      for (int g = 0; g < 4; ++g) { acc[g][0] = 0.f; acc[g][1] = 0.f; }
#pragma unroll
      for (int it = 0; it < 4; ++it) {
        const int k = it * 256 + lane * 4;
        const float4 q0 = h2f4(*(const half4_t*)&w1i0[k]);
        const float4 q1 = h2f4(*(const half4_t*)&w1i1[k]);
        const float4 q2 = h2f4(*(const half4_t*)&w1i2[k]);
        const float4 q3 = h2f4(*(const half4_t*)&w1i3[k]);
#pragma unroll
        for (int j = 0; j < 2; ++j) {
          const float4 xv = *(const float4*)&h0[(bp * 2 + j) * DD + k];
          FMA4(acc[0][j], q0, xv);
          FMA4(acc[1][j], q1, xv);
          FMA4(acc[2][j], q2, xv);
          FMA4(acc[3][j], q3, xv);
        }
      }
#pragma unroll
      for (int it = 0; it < 4; ++it) {
        const int k = it * 256 + lane * 4;
        const float4 q0 = h2f4(*(const half4_t*)&w1h0[k]);
        const float4 q1 = h2f4(*(const half4_t*)&w1h1[k]);
        const float4 q2 = h2f4(*(const half4_t*)&w1h2[k]);
        const float4 q3 = h2f4(*(const half4_t*)&w1h3[k]);
#pragma unroll
        for (int j = 0; j < 2; ++j) {
          const float4 xv = *(const float4*)&h1p[(bp * 2 + j) * DD + k];
          FMA4(acc[0][j], q0, xv);
          FMA4(acc[1][j], q1, xv);
          FMA4(acc[2][j], q2, xv);
          FMA4(acc[3][j], q3, xv);
        }
      }
#pragma unroll
      for (int g = 0; g < 4; ++g) { acc[g][0] = wred(acc[g][0]); acc[g][1] = wred(acc[g][1]); }
      float s[4] = {0.f, 0.f, 0.f, 0.f};
#pragma unroll
      for (int j = 0; j < 2; ++j)
        if (lane == j) { s[0] = acc[0][j]; s[1] = acc[1][j]; s[2] = acc[2][j]; s[3] = acc[3][j]; }
      if (lane < 2) {
        const int b = bp * 2 + lane;
        const float cn = sigm(s[1] + bv1[1]) * c1 + sigm(s[0] + bv1[0]) * tanhf(s[2] + bv1[2]);
        c1 = cn;
        stv(c1_all + (size_t)(t + 1) * (BB * DD) + b * DD + d, cn);
        stv(h1_all + (size_t)(t + 1) * (BB * DD) + b * DD + d,
            sigm(s[3] + bv1[3]) * tanhf(cn));
      }
    }
    gbar2(bar, blk, 512, ++bt);
  }
}

// ---- encWe[m][n] = sum_k enc_out[m][k]*attn_w[n][1024+k], LDS-staged, float4 ----
__global__ __launch_bounds__(512) void encwe2_k(const float* __restrict__ enc_out,
                                                const float* __restrict__ attn_w,
                                                float* __restrict__ encWe) {
  const int tid = threadIdx.x, lane = tid & 63, lw = tid >> 6;
  const int mg = blockIdx.x;
  const int nq = blockIdx.y;
  __shared__ float xsl[16][1024];
  for (int i = tid; i < 16 * 1024 / 4; i += 512)
    *(float4*)&((float*)xsl)[i * 4] =
        *(const float4*)&enc_out[(size_t)mg * 16 * 1024 + i * 4];
  __syncthreads();
#pragma unroll 1
  for (int nn = 0; nn < 8; ++nn) {
    const int n = nq * 64 + lw * 8 + nn;
    float acc[16];
#pragma unroll
    for (int j = 0; j < 16; ++j) acc[j] = 0.f;
#pragma unroll
    for (int it = 0; it < 4; ++it) {
      const int k = it * 256 + lane * 4;
      const float4 w4 = *(const float4*)&attn_w[(size_t)n * 2048 + 1024 + k];
#pragma unroll
      for (int j = 0; j < 16; ++j) {
        const float4 xv = *(const float4*)&xsl[j][k];
        FMA4(acc[j], w4, xv);
      }
    }
#pragma unroll
    for (int j = 0; j < 16; ++j) acc[j] = wred(acc[j]);
    float sel = 0.f;
#pragma unroll
    for (int j = 0; j < 16; ++j)
      if (lane == j) sel = acc[j];
    if (lane < 16) encWe[((size_t)mg * 16 + lane) * 1024 + n] = sel;
  }
}

// ---- logits (fp16 out_w): block = (t, 80 o-rows); h1[t] in LDS ----
__global__ __launch_bounds__(1024, 2) void logits2h_k(const float* __restrict__ h1all,
                                                      const _Float16* __restrict__ ow16,
                                                      const float* __restrict__ out_b,
                                                      float* __restrict__ out) {
  const int tid = threadIdx.x, lane = tid & 63, lw = tid >> 6;
  const int t = blockIdx.x;
  const int oq = blockIdx.y;  // 0..124
  __shared__ float hs[16][1024];
  const float* h1 = h1all + (size_t)t * (BB * DD);
  for (int i = tid; i < BB * DD / 4; i += 1024)
    *(float4*)&((float*)hs)[i * 4] = *(const float4*)&h1[i * 4];
  __syncthreads();
  const int obase = oq * 80 + lw * 5;
#pragma unroll
  for (int p = 0; p < 3; ++p) {
    const int nr = (p < 2) ? 2 : 1;
    const int o0 = obase + p * 2;
    float accA[16], accB[16];
#pragma unroll
    for (int b = 0; b < 16; ++b) { accA[b] = 0.f; accB[b] = 0.f; }
    const _Float16* wr0 = ow16 + (size_t)o0 * DD;
    const _Float16* wr1 = wr0 + DD;
#pragma unroll
    for (int it = 0; it < 4; ++it) {
      const int k = it * 256 + lane * 4;
      const float4 wa = h2f4(*(const half4_t*)&wr0[k]);
      float4 wb = make_float4(0.f, 0.f, 0.f, 0.f);
      if (nr == 2) wb = h2f4(*(const half4_t*)&wr1[k]);
#pragma unroll
      for (int b = 0; b < 16; ++b) {
        const float4 xv = *(const float4*)&hs[b][k];
        FMA4(accA[b], wa, xv);
        if (nr == 2) { FMA4(accB[b], wb, xv); }
      }
    }
#pragma unroll
    for (int b = 0; b < 16; ++b) {
      accA[b] = wred(accA[b]);
      if (nr == 2) accB[b] = wred(accB[b]);
    }
    float sA = 0.f, sB = 0.f;
#pragma unroll
    for (int b = 0; b < 16; ++b)
      if (lane == b) { sA = accA[b]; sB = accB[b]; }
    if (lane < 16) {
      out[(size_t)lane * TT * VO + (size_t)t * VO + o0] = sA + out_b[o0];
      if (nr == 2) out[(size_t)lane * TT * VO + (size_t)t * VO + o0 + 1] = sB + out_b[o0 + 1];
    }
  }
}

extern "C" void kernel_launch(void* const* d_in, const int* in_sizes, int n_in,
                              void* d_out, int out_size, void* d_ws, size_t ws_size,
                              hipStream_t stream) {
  const int* x = (const int*)d_in[0];
  const int* gs = (const int*)d_in[1];
  const float* in_emb = (const float*)d_in[2];
  const float* out_emb = (const float*)d_in[3];
  const float* ewih0 = (const float*)d_in[4];
  const float* ewhh0 = (const float*)d_in[5];
  const float* eb0 = (const float*)d_in[6];
  const float* ewih1 = (const float*)d_in[7];
  const float* ewhh1 = (const float*)d_in[8];
  const float* eb1 = (const float*)d_in[9];
  const float* dwih0 = (const float*)d_in[10];
  const float* dwhh0 = (const float*)d_in[11];
  const float* db0 = (const float*)d_in[12];
  const float* dwih1 = (const float*)d_in[13];
  const float* dwhh1 = (const float*)d_in[14];
  const float* db1 = (const float*)d_in[15];
  const float* attn_w = (const float*)d_in[16];
  const float* attn_b = (const float*)d_in[17];
  const float* attn_v = (const float*)d_in[18];
  const float* out_w = (const float*)d_in[19];
  const float* out_b = (const float*)d_in[20];
  float* out = (float*)d_out;

  float* ws = (float*)d_ws;
  size_t off = 0;
  auto alloc = [&](size_t n) { float* p = ws + off; off += n; return p; };
  // ---- memset region: 5 barrier domains + zeros + enc h_all slot-0s ----
  unsigned* bar = (unsigned*)alloc(5 * 16384);  // encL0 d0/d1, encL1 d0/d1, dec
  float* zeros = alloc(BB * DD);
  float* ehA = alloc((size_t)(SS + 1) * 2 * BB * HH);
  float* ehB = alloc(2 * BB * HH);
  const size_t state_n = off;
  alloc((size_t)SS * 2 * BB * HH);  // enc L1 h_all slots 1..128 (contiguous w/ ehB)
  // ---- fp16 weight copies (decoder LSTM + attn_w + out_w) ----
  _Float16* w16i0 = (_Float16*)alloc(4096 * 1536 / 2);
  _Float16* w16h0 = (_Float16*)alloc(4096 * 1024 / 2);
  _Float16* w16i1 = (_Float16*)alloc(4096 * 1024 / 2);
  _Float16* w16h1 = (_Float16*)alloc(4096 * 1024 / 2);
  _Float16* aw16 = (_Float16*)alloc(1024 * 2048 / 2);
  _Float16* ow16 = (_Float16*)alloc((size_t)VO * DD / 2);
  // ---- in-kernel write-once / fully-written buffers ----
  float* h0_all = alloc((size_t)(TT + 1) * BB * DD);
  float* h1_all = alloc((size_t)(TT + 1) * BB * DD);
  float* c1_all = alloc((size_t)(TT + 1) * BB * DD);
  float* wtd_all = alloc((size_t)TT * BB * DD);
  float* qW_all = alloc((size_t)TT * BB * DD);
  float* scores_all = alloc((size_t)TT * BB * SS);
  float* xs_emb = alloc((size_t)SS * BB * EE);
  float* gs_emb = alloc((size_t)TT * BB * EE);
  float* l0 = alloc((size_t)SS * BB * (2 * HH));
  float* enc_out = alloc((size_t)BB * SS * (2 * HH));
  float* encWe = alloc((size_t)BB * SS * DD);
  float* gxA = alloc(2ull * 2048ull * 2048ull);
  (void)ws_size; (void)in_sizes; (void)n_in; (void)out_size;

  hipMemsetAsync(d_ws, 0, state_n * sizeof(float), stream);

  // fp16 weight conversion (parallel, independent)
  f2h_k<<<(4096 * 1536 / 8 + 255) / 256, 256, 0, stream>>>(dwih0, w16i0, 4096 * 1536 / 8);
  f2h_k<<<(4096 * 1024 / 8 + 255) / 256, 256, 0, stream>>>(dwhh0, w16h0, 4096 * 1024 / 8);
  f2h_k<<<(4096 * 1024 / 8 + 255) / 256, 256, 0, stream>>>(dwih1, w16i1, 4096 * 1024 / 8);
  f2h_k<<<(4096 * 1024 / 8 + 255) / 256, 256, 0, stream>>>(dwhh1, w16h1, 4096 * 1024 / 8);
  f2h_k<<<(1024 * 2048 / 8 + 255) / 256, 256, 0, stream>>>(attn_w, aw16, 1024 * 2048 / 8);
  f2h_k<<<(VO * DD / 8 + 255) / 256, 256, 0, stream>>>(out_w, ow16, VO * DD / 8);

  gather_k<<<dim3(SS, BB), 128, 0, stream>>>(x, in_emb, xs_emb, SS);
  gather_k<<<dim3(TT, BB), 128, 0, stream>>>(gs, out_emb, gs_emb, TT);

  // encoder layer 0: parallel x-part (W L1-resident), then persistent recurrence
  gemv16c_k<EE><<<dim3(512, 2), 256, 0, stream>>>(
      xs_emb, EE, ewih0, EE, gxA, 2048, (size_t)4 * HH * EE, 2048ull * 2048ull);
  enc_mega7_k<<<256, 512, 0, stream>>>(gxA, ewhh0, eb0, ehA, l0, BB * 2 * HH, 2 * HH, bar);
  // encoder layer 1
  gemv16c_k<2 * HH><<<dim3(512, 2), 256, 0, stream>>>(
      l0, 2 * HH, ewih1, 2 * HH, gxA, 2048, (size_t)4 * HH * 2 * HH, 2048ull * 2048ull);
  enc_mega7_k<<<256, 512, 0, stream>>>(gxA, ewhh1, eb1, ehB, enc_out, 2 * HH, SS * 2 * HH,
                                       bar + 2 * 16384);
  // step-invariant attention term (fp32)
  encwe2_k<<<dim3(128, 16), 512, 0, stream>>>(enc_out, attn_w, encWe);

  // persistent decoder: 512 blocks (2/CU, ~100% occupancy), fp16 weights
  dec_megaA_k<<<512, 1024, 0, stream>>>(gs_emb, encWe, enc_out, aw16, attn_b, attn_v,
                                        w16i0, w16h0, db0, w16i1, w16h1, db1, zeros,
                                        h0_all, h1_all, c1_all, wtd_all, qW_all,
                                        scores_all, bar + 4 * 16384);

  // all logits (h1 slots 1..128), fp16 out_w
  logits2h_k<<<dim3(TT, 125), 1024, 0, stream>>>(h1_all + BB * DD, ow16, out_b, out);
}

// Round 15
// 15432.457 us; speedup vs baseline: 2.1551x; 2.1551x over previous
//
#include <hip/hip_runtime.h>

#define BB 16
#define SS 128
#define TT 128
#define EE 512
#define HH 512
#define DD 1024
#define VO 10000

typedef _Float16 half4_t __attribute__((ext_vector_type(4)));
typedef _Float16 half8_t __attribute__((ext_vector_type(8)));

#define FMA4(A, W, X)              \
  A = fmaf((W).x, (X).x, A);       \
  A = fmaf((W).y, (X).y, A);       \
  A = fmaf((W).z, (X).z, A);       \
  A = fmaf((W).w, (X).w, A)

__device__ __forceinline__ float4 h2f4(half4_t h) {
  return make_float4((float)h[0], (float)h[1], (float)h[2], (float)h[3]);
}

__device__ __forceinline__ float wred(float s) {
#pragma unroll
  for (int off = 32; off >= 1; off >>= 1) s += __shfl_xor(s, off, 64);
  return s;
}
__device__ __forceinline__ float sigm(float x) { return 1.f / (1.f + expf(-x)); }

__device__ __forceinline__ void stv(float* p, float v) {
  __hip_atomic_store(p, v, __ATOMIC_RELAXED, __HIP_MEMORY_SCOPE_AGENT);
}

// ---- grid barrier v2: flag-scan, relaxed-only (validated R7-R13) ----
__device__ __forceinline__ void gbar2(unsigned* bar, int lb, int nblk, unsigned target) {
  asm volatile("s_waitcnt vmcnt(0) lgkmcnt(0)" ::: "memory");
  __syncthreads();
  if (threadIdx.x == 0)
    __hip_atomic_store(bar + lb * 16, target, __ATOMIC_RELAXED, __HIP_MEMORY_SCOPE_AGENT);
  if (lb == 0) {
    for (int i = threadIdx.x; i < nblk; i += blockDim.x)
      while (__hip_atomic_load(bar + i * 16, __ATOMIC_RELAXED, __HIP_MEMORY_SCOPE_AGENT) <
             target)
        __builtin_amdgcn_s_sleep(1);
    __syncthreads();
    if (threadIdx.x == 0)
      __hip_atomic_store(bar + 8192, target, __ATOMIC_RELAXED, __HIP_MEMORY_SCOPE_AGENT);
  }
  if (threadIdx.x == 0)
    while (__hip_atomic_load(bar + 8192, __ATOMIC_RELAXED, __HIP_MEMORY_SCOPE_AGENT) <
           target)
      __builtin_amdgcn_s_sleep(1);
  __syncthreads();
}

// ---- fp32 -> fp16 conversion (8 elems/thread) ----
__global__ void f2h_k(const float* __restrict__ src, _Float16* __restrict__ dst, int n8) {
  const int i = blockIdx.x * blockDim.x + threadIdx.x;
  if (i < n8) {
    const float4 a = *(const float4*)&src[i * 8];
    const float4 b = *(const float4*)&src[i * 8 + 4];
    half8_t h;
    h[0] = a.x; h[1] = a.y; h[2] = a.z; h[3] = a.w;
    h[4] = b.x; h[5] = b.y; h[6] = b.z; h[7] = b.w;
    *(half8_t*)&dst[i * 8] = h;
  }
}

// ---- embedding gather (padding_idx=0 -> zeros), out layout [Sn][B][E] ----
__global__ void gather_k(const int* __restrict__ idx, const float* __restrict__ emb,
                         float* __restrict__ out, int Sn) {
  const int s = blockIdx.x, b = blockIdx.y, tid = threadIdx.x;
  const int id = idx[b * Sn + s];
  float4 v = make_float4(0.f, 0.f, 0.f, 0.f);
  if (id != 0) v = ((const float4*)(emb + (size_t)id * EE))[tid];
  ((float4*)(out + ((size_t)s * BB + b) * EE))[tid] = v;
}

// ---- G[z][n][m]: mg loop inside -> W rows stay L1-resident ----
template <int K>
__global__ void gemv16c_k(const float* __restrict__ X, int ldx,
                          const float* __restrict__ W, int ldw,
                          float* __restrict__ G, int M, size_t wz, size_t gz) {
  const int lane = threadIdx.x & 63;
  const int n = blockIdx.x * 4 + (threadIdx.x >> 6);
  const int z = blockIdx.y;
  const float* Wn = W + (size_t)z * wz + (size_t)n * ldw;
#pragma unroll 1
  for (int mg = 0; mg < M / 16; ++mg) {
    const float* Xr = X + (size_t)mg * 16 * ldx;
    float acc[16];
#pragma unroll
    for (int j = 0; j < 16; ++j) acc[j] = 0.f;
#pragma unroll
    for (int it = 0; it < K / 256; ++it) {
      const int k = it * 256 + lane * 4;
      const float4 w4 = *(const float4*)&Wn[k];
#pragma unroll
      for (int j = 0; j < 16; ++j) {
        const float4 xv = *(const float4*)&Xr[(size_t)j * ldx + k];
        FMA4(acc[j], w4, xv);
      }
    }
#pragma unroll
    for (int j = 0; j < 16; ++j) acc[j] = wred(acc[j]);
    float sel = 0.f;
#pragma unroll
    for (int j = 0; j < 16; ++j)
      if (lane == j) sel = acc[j];
    if (lane < 16) G[(size_t)z * gz + (size_t)n * M + mg * 16 + lane] = sel;
  }
}

// ---- persistent encoder: 256 blocks x 512 thr (unchanged, proven) ----
__global__ __launch_bounds__(512, 4) void enc_mega7_k(
    const float* __restrict__ gx, const float* __restrict__ whh,
    const float* __restrict__ bias, float* __restrict__ h_all,
    float* __restrict__ seq, int seq_ts, int seq_bs, unsigned* __restrict__ barbase) {
  const int tid = threadIdx.x, lane = tid & 63, lw = tid >> 6;
  const int dir = blockIdx.x >> 7;
  const int lb = blockIdx.x & 127;
  const int w2 = lb * 8 + lw;
  const int d = w2 >> 1, bq = w2 & 1;
  unsigned* bar = barbase + dir * 16384;

  __shared__ float hs[16][512];

  float wr[4][8];
  const float* wsrc = whh + (size_t)dir * (4 * HH * HH);
#pragma unroll
  for (int g = 0; g < 4; ++g)
#pragma unroll
    for (int j = 0; j < 8; ++j)
      wr[g][j] = wsrc[(size_t)(g * HH + d) * HH + j * 64 + lane];
  float bv[4];
#pragma unroll
  for (int g = 0; g < 4; ++g) bv[g] = bias[dir * 4 * HH + g * HH + d];
  const float* gxz = gx + (size_t)dir * ((size_t)4 * HH * 2048);
  float creg = 0.f;
  unsigned bt = 0;

  for (int t = 0; t < SS; ++t) {
    const int idx = dir ? (SS - 1 - t) : t;
    const float* hp = h_all + ((size_t)t * 2 + dir) * (BB * HH);
    for (int i = tid; i < BB * HH / 4; i += 512)
      *(float4*)&((float*)hs)[i * 4] = *(const float4*)&hp[i * 4];
    __syncthreads();
    float acc[4][8];
#pragma unroll
    for (int g = 0; g < 4; ++g)
#pragma unroll
      for (int j = 0; j < 8; ++j) acc[g][j] = 0.f;
#pragma unroll
    for (int kb = 0; kb < 8; ++kb) {
      const int k = kb * 64 + lane;
#pragma unroll
      for (int j = 0; j < 8; ++j) {
        const float xv = hs[bq * 8 + j][k];
#pragma unroll
        for (int g = 0; g < 4; ++g) acc[g][j] = fmaf(wr[g][kb], xv, acc[g][j]);
      }
    }
#pragma unroll
    for (int g = 0; g < 4; ++g)
#pragma unroll
      for (int j = 0; j < 8; ++j) acc[g][j] = wred(acc[g][j]);
    float s0 = 0.f, s1 = 0.f, s2 = 0.f, s3 = 0.f;
#pragma unroll
    for (int j = 0; j < 8; ++j)
      if (lane == j) { s0 = acc[0][j]; s1 = acc[1][j]; s2 = acc[2][j]; s3 = acc[3][j]; }
    if (lane < 8) {
      const int b = bq * 8 + lane;
      const int m = idx * 16 + b;
      const float gi = sigm(s0 + bv[0] + gxz[(size_t)(0 * HH + d) * 2048 + m]);
      const float gf = sigm(s1 + bv[1] + gxz[(size_t)(1 * HH + d) * 2048 + m]);
      const float gg = tanhf(s2 + bv[2] + gxz[(size_t)(2 * HH + d) * 2048 + m]);
      const float go = sigm(s3 + bv[3] + gxz[(size_t)(3 * HH + d) * 2048 + m]);
      const float cn = gf * creg + gi * gg;
      creg = cn;
      const float hv = go * tanhf(cn);
      stv(h_all + ((size_t)(t + 1) * 2 + dir) * (BB * HH) + b * HH + d, hv);
      seq[(size_t)idx * seq_ts + (size_t)b * seq_bs + dir * HH + d] = hv;
    }
    gbar2(bar, lb, 128, ++bt);
  }
}

// ---- persistent decoder (R12 proven structure, fp16 weights): 256 blocks x
// 1024 thr; wave = (d, batch-quad) owns all 4 gate rows; 5 barriers/step ----
__global__ __launch_bounds__(1024, 4) void dec_mega7h_k(
    const float* __restrict__ gs_emb, const float* __restrict__ encWe,
    const float* __restrict__ enc_out, const _Float16* __restrict__ aw16,
    const float* __restrict__ attn_b, const float* __restrict__ attn_v,
    const _Float16* __restrict__ w16i0, const _Float16* __restrict__ w16h0,
    const float* __restrict__ b0, const _Float16* __restrict__ w16i1,
    const _Float16* __restrict__ w16h1, const float* __restrict__ b1,
    const float* __restrict__ zeros, float* __restrict__ h0_all,
    float* __restrict__ h1_all, float* __restrict__ c1_all, float* __restrict__ wtd_all,
    float* __restrict__ qW_all, float* __restrict__ scores_all,
    unsigned* __restrict__ bar) {
  const int tid = threadIdx.x, lane = tid & 63, lw = tid >> 6;
  const int blk = blockIdx.x;
  const int w = blk * 16 + lw;  // 0..4095
  const int d = w >> 2, bq = w & 3;
  const int b_att = blk >> 4, shard = blk & 15;

  __shared__ float xch[4][4][16];
  __shared__ float sco[SS];
  __shared__ float sred[16][64];

  const _Float16* w0i0 = w16i0 + (size_t)(0 * DD + d) * 1536;
  const _Float16* w0i1 = w16i0 + (size_t)(1 * DD + d) * 1536;
  const _Float16* w0i2 = w16i0 + (size_t)(2 * DD + d) * 1536;
  const _Float16* w0i3 = w16i0 + (size_t)(3 * DD + d) * 1536;
  const _Float16* w0h0 = w16h0 + (size_t)(0 * DD + d) * 1024;
  const _Float16* w0h1 = w16h0 + (size_t)(1 * DD + d) * 1024;
  const _Float16* w0h2 = w16h0 + (size_t)(2 * DD + d) * 1024;
  const _Float16* w0h3 = w16h0 + (size_t)(3 * DD + d) * 1024;
  const _Float16* w1i0 = w16i1 + (size_t)(0 * DD + d) * 1024;
  const _Float16* w1i1 = w16i1 + (size_t)(1 * DD + d) * 1024;
  const _Float16* w1i2 = w16i1 + (size_t)(2 * DD + d) * 1024;
  const _Float16* w1i3 = w16i1 + (size_t)(3 * DD + d) * 1024;
  const _Float16* w1h0 = w16h1 + (size_t)(0 * DD + d) * 1024;
  const _Float16* w1h1 = w16h1 + (size_t)(1 * DD + d) * 1024;
  const _Float16* w1h2 = w16h1 + (size_t)(2 * DD + d) * 1024;
  const _Float16* w1h3 = w16h1 + (size_t)(3 * DD + d) * 1024;
  float bv0[4], bv1[4];
#pragma unroll
  for (int g = 0; g < 4; ++g) { bv0[g] = b0[g * DD + d]; bv1[g] = b1[g * DD + d]; }
  const float abv = attn_b[d];
  float c0 = 0.f, c1 = 0.f;
  unsigned bt = 0;

  // ---- prime layer 0: zero input & state -> c0 identical for every batch.
  // FIX vs R12: every wave initializes its own c0 (R12 only did bq==0).
  {
    const float cn = sigm(bv0[0]) * tanhf(bv0[2]);
    c0 = cn;
    if (bq == 0 && lane < 16)
      stv(h0_all + lane * DD + d, sigm(bv0[3]) * tanhf(cn));
  }
  gbar2(bar, blk, 256, ++bt);
  // ---- prime layer 1: rows w1i . h0_all[0]  (h1prev = 0) ----
  {
    float acc[4][4];
#pragma unroll
    for (int g = 0; g < 4; ++g)
#pragma unroll
      for (int j = 0; j < 4; ++j) acc[g][j] = 0.f;
#pragma unroll
    for (int it = 0; it < 4; ++it) {
      const int k = it * 256 + lane * 4;
      const float4 q0 = h2f4(*(const half4_t*)&w1i0[k]);
      const float4 q1 = h2f4(*(const half4_t*)&w1i1[k]);
      const float4 q2 = h2f4(*(const half4_t*)&w1i2[k]);
      const float4 q3 = h2f4(*(const half4_t*)&w1i3[k]);
#pragma unroll
      for (int j = 0; j < 4; ++j) {
        const float4 xv = *(const float4*)&h0_all[(bq * 4 + j) * DD + k];
        FMA4(acc[0][j], q0, xv);
        FMA4(acc[1][j], q1, xv);
        FMA4(acc[2][j], q2, xv);
        FMA4(acc[3][j], q3, xv);
      }
    }
#pragma unroll
    for (int g = 0; g < 4; ++g)
#pragma unroll
      for (int j = 0; j < 4; ++j) acc[g][j] = wred(acc[g][j]);
    float s[4] = {0.f, 0.f, 0.f, 0.f};
#pragma unroll
    for (int j = 0; j < 4; ++j)
      if (lane == j) { s[0] = acc[0][j]; s[1] = acc[1][j]; s[2] = acc[2][j]; s[3] = acc[3][j]; }
    if (lane < 4) {
      const int b = bq * 4 + lane;
      const float cn = sigm(s[0] + bv1[0]) * tanhf(s[2] + bv1[2]);
      c1 = cn;
      stv(c1_all + b * DD + d, cn);
      stv(h1_all + b * DD + d, sigm(s[3] + bv1[3]) * tanhf(cn));
    }
  }
  gbar2(bar, blk, 256, ++bt);

  for (int t = 0; t < TT; ++t) {
    // ===== qW[b,d] = attn_b[d] + c1[b,:].attn_w[d,:1024]  (fp16 row) =====
    {
      const float* cb = c1_all + (size_t)t * (BB * DD);
      float qa[4] = {0.f, 0.f, 0.f, 0.f};
#pragma unroll
      for (int it = 0; it < 4; ++it) {
        const int k = it * 256 + lane * 4;
        const float4 w4 = h2f4(*(const half4_t*)&aw16[(size_t)d * 2048 + k]);
#pragma unroll
        for (int j = 0; j < 4; ++j) {
          const float4 xv = *(const float4*)&cb[(bq * 4 + j) * DD + k];
          FMA4(qa[j], w4, xv);
        }
      }
#pragma unroll
      for (int j = 0; j < 4; ++j) qa[j] = wred(qa[j]);
      float sel = 0.f;
#pragma unroll
      for (int j = 0; j < 4; ++j)
        if (lane == j) sel = qa[j];
      if (lane < 4)
        stv(qW_all + (size_t)t * (BB * DD) + (bq * 4 + lane) * DD + d, sel + abv);
    }
    gbar2(bar, blk, 256, ++bt);
    // ===== scores[b_att, shard*8+lw] =====
    if (lw < 8) {
      const int s = shard * 8 + lw;
      const float* ew = encWe + ((size_t)(b_att * SS + s)) * DD;
      const float* qb = qW_all + (size_t)t * (BB * DD) + b_att * DD;
      float a = 0.f;
#pragma unroll
      for (int it = 0; it < 4; ++it) {
        const int k = it * 256 + lane * 4;
        const float4 e4 = *(const float4*)&ew[k];
        const float4 q4 = *(const float4*)&qb[k];
        const float4 v4 = *(const float4*)&attn_v[k];
        a += v4.x * tanhf(q4.x + e4.x) + v4.y * tanhf(q4.y + e4.y) +
             v4.z * tanhf(q4.z + e4.z) + v4.w * tanhf(q4.w + e4.w);
      }
      a = wred(a);
      if (lane == 0) stv(scores_all + (size_t)t * (BB * SS) + b_att * SS + s, a);
    }
    gbar2(bar, blk, 256, ++bt);
    // ===== softmax + weighted sum -> wtd_all[t][b_att][shard*64+lane] =====
    {
      if (tid < SS) sco[tid] = scores_all[(size_t)t * (BB * SS) + b_att * SS + tid];
      __syncthreads();
      float m = -1e30f;
      for (int s = 0; s < SS; ++s) m = fmaxf(m, sco[s]);
      __syncthreads();
      if (tid < SS) sco[tid] = expf(sco[tid] - m);
      __syncthreads();
      float sum = 0.f;
      for (int s = 0; s < SS; ++s) sum += sco[s];
      const float inv = 1.f / sum;
      float p = 0.f;
#pragma unroll
      for (int i = 0; i < 8; ++i) {
        const int s = lw * 8 + i;
        p += sco[s] * enc_out[((size_t)(b_att * SS + s)) * DD + shard * 64 + lane];
      }
      sred[lw][lane] = p;
      __syncthreads();
      if (lw == 0) {
        float a2 = 0.f;
#pragma unroll
        for (int i = 0; i < 16; ++i) a2 += sred[i][lane];
        stv(wtd_all + (size_t)t * (BB * DD) + b_att * DD + shard * 64 + lane, a2 * inv);
      }
    }
    gbar2(bar, blk, 256, ++bt);
    // ===== decoder layer 0: K = wtd(1024) | emb(512) | h0prev(1024) =====
    {
      const float* xw = wtd_all + (size_t)t * (BB * DD);
      const float* em = t ? gs_emb + (size_t)(t - 1) * (BB * EE) : zeros;
      const float* hp = h0_all + (size_t)t * (BB * DD);
      float acc[4][4];
#pragma unroll
      for (int g = 0; g < 4; ++g)
#pragma unroll
        for (int j = 0; j < 4; ++j) acc[g][j] = 0.f;
#pragma unroll
      for (int it = 0; it < 4; ++it) {
        const int k = it * 256 + lane * 4;
        const float4 q0 = h2f4(*(const half4_t*)&w0i0[k]);
        const float4 q1 = h2f4(*(const half4_t*)&w0i1[k]);
        const float4 q2 = h2f4(*(const half4_t*)&w0i2[k]);
        const float4 q3 = h2f4(*(const half4_t*)&w0i3[k]);
#pragma unroll
        for (int j = 0; j < 4; ++j) {
          const float4 xv = *(const float4*)&xw[(bq * 4 + j) * DD + k];
          FMA4(acc[0][j], q0, xv);
          FMA4(acc[1][j], q1, xv);
          FMA4(acc[2][j], q2, xv);
          FMA4(acc[3][j], q3, xv);
        }
      }
#pragma unroll
      for (int it = 4; it < 6; ++it) {
        const int k = it * 256 + lane * 4;
        const float4 q0 = h2f4(*(const half4_t*)&w0i0[k]);
        const float4 q1 = h2f4(*(const half4_t*)&w0i1[k]);
        const float4 q2 = h2f4(*(const half4_t*)&w0i2[k]);
        const float4 q3 = h2f4(*(const half4_t*)&w0i3[k]);
#pragma unroll
        for (int j = 0; j < 4; ++j) {
          const float4 xv = *(const float4*)&em[(bq * 4 + j) * EE + (k - 1024)];
          FMA4(acc[0][j], q0, xv);
          FMA4(acc[1][j], q1, xv);
          FMA4(acc[2][j], q2, xv);
          FMA4(acc[3][j], q3, xv);
        }
      }
#pragma unroll
      for (int it = 0; it < 4; ++it) {
        const int k = it * 256 + lane * 4;
        const float4 q0 = h2f4(*(const half4_t*)&w0h0[k]);
        const float4 q1 = h2f4(*(const half4_t*)&w0h1[k]);
        const float4 q2 = h2f4(*(const half4_t*)&w0h2[k]);
        const float4 q3 = h2f4(*(const half4_t*)&w0h3[k]);
#pragma unroll
        for (int j = 0; j < 4; ++j) {
          const float4 xv = *(const float4*)&hp[(bq * 4 + j) * DD + k];
          FMA4(acc[0][j], q0, xv);
          FMA4(acc[1][j], q1, xv);
          FMA4(acc[2][j], q2, xv);
          FMA4(acc[3][j], q3, xv);
        }
      }
#pragma unroll
      for (int g = 0; g < 4; ++g)
#pragma unroll
        for (int j = 0; j < 4; ++j) acc[g][j] = wred(acc[g][j]);
      float s[4] = {0.f, 0.f, 0.f, 0.f};
#pragma unroll
      for (int j = 0; j < 4; ++j)
        if (lane == j) { s[0] = acc[0][j]; s[1] = acc[1][j]; s[2] = acc[2][j]; s[3] = acc[3][j]; }
      if (lane < 4) {
        const int b = bq * 4 + lane;
        const float cn = sigm(s[1] + bv0[1]) * c0 + sigm(s[0] + bv0[0]) * tanhf(s[2] + bv0[2]);
        c0 = cn;
        stv(h0_all + (size_t)(t + 1) * (BB * DD) + b * DD + d,
            sigm(s[3] + bv0[3]) * tanhf(cn));
      }
    }
    gbar2(bar, blk, 256, ++bt);
    // ===== decoder layer 1: K = h0new(1024) | h1prev(1024) =====
    {
      const float* h0 = h0_all + (size_t)(t + 1) * (BB * DD);
      const float* h1p = h1_all + (size_t)t * (BB * DD);
      float acc[4][4];
#pragma unroll
      for (int g = 0; g < 4; ++g)
#pragma unroll
        for (int j = 0; j < 4; ++j) acc[g][j] = 0.f;
#pragma unroll
      for (int it = 0; it < 4; ++it) {
        const int k = it * 256 + lane * 4;
        const float4 q0 = h2f4(*(const half4_t*)&w1i0[k]);
        const float4 q1 = h2f4(*(const half4_t*)&w1i1[k]);
        const float4 q2 = h2f4(*(const half4_t*)&w1i2[k]);
        const float4 q3 = h2f4(*(const half4_t*)&w1i3[k]);
#pragma unroll
        for (int j = 0; j < 4; ++j) {
          const float4 xv = *(const float4*)&h0[(bq * 4 + j) * DD + k];
          FMA4(acc[0][j], q0, xv);
          FMA4(acc[1][j], q1, xv);
          FMA4(acc[2][j], q2, xv);
          FMA4(acc[3][j], q3, xv);
        }
      }
#pragma unroll
      for (int it = 0; it < 4; ++it) {
        const int k = it * 256 + lane * 4;
        const float4 q0 = h2f4(*(const half4_t*)&w1h0[k]);
        const float4 q1 = h2f4(*(const half4_t*)&w1h1[k]);
        const float4 q2 = h2f4(*(const half4_t*)&w1h2[k]);
        const float4 q3 = h2f4(*(const half4_t*)&w1h3[k]);
#pragma unroll
        for (int j = 0; j < 4; ++j) {
          const float4 xv = *(const float4*)&h1p[(bq * 4 + j) * DD + k];
          FMA4(acc[0][j], q0, xv);
          FMA4(acc[1][j], q1, xv);
          FMA4(acc[2][j], q2, xv);
          FMA4(acc[3][j], q3, xv);
        }
      }
#pragma unroll
      for (int g = 0; g < 4; ++g)
#pragma unroll
        for (int j = 0; j < 4; ++j) acc[g][j] = wred(acc[g][j]);
      float s[4] = {0.f, 0.f, 0.f, 0.f};
#pragma unroll
      for (int j = 0; j < 4; ++j)
        if (lane == j) { s[0] = acc[0][j]; s[1] = acc[1][j]; s[2] = acc[2][j]; s[3] = acc[3][j]; }
      if (lane < 4) {
        const int b = bq * 4 + lane;
        const float cn = sigm(s[1] + bv1[1]) * c1 + sigm(s[0] + bv1[0]) * tanhf(s[2] + bv1[2]);
        c1 = cn;
        stv(c1_all + (size_t)(t + 1) * (BB * DD) + b * DD + d, cn);
        stv(h1_all + (size_t)(t + 1) * (BB * DD) + b * DD + d,
            sigm(s[3] + bv1[3]) * tanhf(cn));
      }
    }
    gbar2(bar, blk, 256, ++bt);
  }
}

// ---- encWe[m][n] = sum_k enc_out[m][k]*attn_w[n][1024+k], LDS-staged, float4 ----
__global__ __launch_bounds__(512) void encwe2_k(const float* __restrict__ enc_out,
                                                const float* __restrict__ attn_w,
                                                float* __restrict__ encWe) {
  const int tid = threadIdx.x, lane = tid & 63, lw = tid >> 6;
  const int mg = blockIdx.x;
  const int nq = blockIdx.y;
  __shared__ float xsl[16][1024];
  for (int i = tid; i < 16 * 1024 / 4; i += 512)
    *(float4*)&((float*)xsl)[i * 4] =
        *(const float4*)&enc_out[(size_t)mg * 16 * 1024 + i * 4];
  __syncthreads();
#pragma unroll 1
  for (int nn = 0; nn < 8; ++nn) {
    const int n = nq * 64 + lw * 8 + nn;
    float acc[16];
#pragma unroll
    for (int j = 0; j < 16; ++j) acc[j] = 0.f;
#pragma unroll
    for (int it = 0; it < 4; ++it) {
      const int k = it * 256 + lane * 4;
      const float4 w4 = *(const float4*)&attn_w[(size_t)n * 2048 + 1024 + k];
#pragma unroll
      for (int j = 0; j < 16; ++j) {
        const float4 xv = *(const float4*)&xsl[j][k];
        FMA4(acc[j], w4, xv);
      }
    }
#pragma unroll
    for (int j = 0; j < 16; ++j) acc[j] = wred(acc[j]);
    float sel = 0.f;
#pragma unroll
    for (int j = 0; j < 16; ++j)
      if (lane == j) sel = acc[j];
    if (lane < 16) encWe[((size_t)mg * 16 + lane) * 1024 + n] = sel;
  }
}

// ---- logits (fp16 out_w): block = (t, 80 o-rows); h1[t] in LDS ----
__global__ __launch_bounds__(1024, 2) void logits2h_k(const float* __restrict__ h1all,
                                                      const _Float16* __restrict__ ow16,
                                                      const float* __restrict__ out_b,
                                                      float* __restrict__ out) {
  const int tid = threadIdx.x, lane = tid & 63, lw = tid >> 6;
  const int t = blockIdx.x;
  const int oq = blockIdx.y;  // 0..124
  __shared__ float hs[16][1024];
  const float* h1 = h1all + (size_t)t * (BB * DD);
  for (int i = tid; i < BB * DD / 4; i += 1024)
    *(float4*)&((float*)hs)[i * 4] = *(const float4*)&h1[i * 4];
  __syncthreads();
  const int obase = oq * 80 + lw * 5;
#pragma unroll
  for (int p = 0; p < 3; ++p) {
    const int nr = (p < 2) ? 2 : 1;
    const int o0 = obase + p * 2;
    float accA[16], accB[16];
#pragma unroll
    for (int b = 0; b < 16; ++b) { accA[b] = 0.f; accB[b] = 0.f; }
    const _Float16* wr0 = ow16 + (size_t)o0 * DD;
    const _Float16* wr1 = wr0 + DD;
#pragma unroll
    for (int it = 0; it < 4; ++it) {
      const int k = it * 256 + lane * 4;
      const float4 wa = h2f4(*(const half4_t*)&wr0[k]);
      float4 wb = make_float4(0.f, 0.f, 0.f, 0.f);
      if (nr == 2) wb = h2f4(*(const half4_t*)&wr1[k]);
#pragma unroll
      for (int b = 0; b < 16; ++b) {
        const float4 xv = *(const float4*)&hs[b][k];
        FMA4(accA[b], wa, xv);
        if (nr == 2) { FMA4(accB[b], wb, xv); }
      }
    }
#pragma unroll
    for (int b = 0; b < 16; ++b) {
      accA[b] = wred(accA[b]);
      if (nr == 2) accB[b] = wred(accB[b]);
    }
    float sA = 0.f, sB = 0.f;
#pragma unroll
    for (int b = 0; b < 16; ++b)
      if (lane == b) { sA = accA[b]; sB = accB[b]; }
    if (lane < 16) {
      out[(size_t)lane * TT * VO + (size_t)t * VO + o0] = sA + out_b[o0];
      if (nr == 2) out[(size_t)lane * TT * VO + (size_t)t * VO + o0 + 1] = sB + out_b[o0 + 1];
    }
  }
}

extern "C" void kernel_launch(void* const* d_in, const int* in_sizes, int n_in,
                              void* d_out, int out_size, void* d_ws, size_t ws_size,
                              hipStream_t stream) {
  const int* x = (const int*)d_in[0];
  const int* gs = (const int*)d_in[1];
  const float* in_emb = (const float*)d_in[2];
  const float* out_emb = (const float*)d_in[3];
  const float* ewih0 = (const float*)d_in[4];
  const float* ewhh0 = (const float*)d_in[5];
  const float* eb0 = (const float*)d_in[6];
  const float* ewih1 = (const float*)d_in[7];
  const float* ewhh1 = (const float*)d_in[8];
  const float* eb1 = (const float*)d_in[9];
  const float* dwih0 = (const float*)d_in[10];
  const float* dwhh0 = (const float*)d_in[11];
  const float* db0 = (const float*)d_in[12];
  const float* dwih1 = (const float*)d_in[13];
  const float* dwhh1 = (const float*)d_in[14];
  const float* db1 = (const float*)d_in[15];
  const float* attn_w = (const float*)d_in[16];
  const float* attn_b = (const float*)d_in[17];
  const float* attn_v = (const float*)d_in[18];
  const float* out_w = (const float*)d_in[19];
  const float* out_b = (const float*)d_in[20];
  float* out = (float*)d_out;

  float* ws = (float*)d_ws;
  size_t off = 0;
  auto alloc = [&](size_t n) { float* p = ws + off; off += n; return p; };
  // ---- memset region: 5 barrier domains + zeros + enc h_all slot-0s ----
  unsigned* bar = (unsigned*)alloc(5 * 16384);  // encL0 d0/d1, encL1 d0/d1, dec
  float* zeros = alloc(BB * DD);
  float* ehA = alloc((size_t)(SS + 1) * 2 * BB * HH);
  float* ehB = alloc(2 * BB * HH);
  const size_t state_n = off;
  alloc((size_t)SS * 2 * BB * HH);  // enc L1 h_all slots 1..128 (contiguous w/ ehB)
  // ---- fp16 weight copies (decoder LSTM + attn_w + out_w) ----
  _Float16* w16i0 = (_Float16*)alloc(4096 * 1536 / 2);
  _Float16* w16h0 = (_Float16*)alloc(4096 * 1024 / 2);
  _Float16* w16i1 = (_Float16*)alloc(4096 * 1024 / 2);
  _Float16* w16h1 = (_Float16*)alloc(4096 * 1024 / 2);
  _Float16* aw16 = (_Float16*)alloc(1024 * 2048 / 2);
  _Float16* ow16 = (_Float16*)alloc((size_t)VO * DD / 2);
  // ---- in-kernel write-once / fully-written buffers ----
  float* h0_all = alloc((size_t)(TT + 1) * BB * DD);
  float* h1_all = alloc((size_t)(TT + 1) * BB * DD);
  float* c1_all = alloc((size_t)(TT + 1) * BB * DD);
  float* wtd_all = alloc((size_t)TT * BB * DD);
  float* qW_all = alloc((size_t)TT * BB * DD);
  float* scores_all = alloc((size_t)TT * BB * SS);
  float* xs_emb = alloc((size_t)SS * BB * EE);
  float* gs_emb = alloc((size_t)TT * BB * EE);
  float* l0 = alloc((size_t)SS * BB * (2 * HH));
  float* enc_out = alloc((size_t)BB * SS * (2 * HH));
  float* encWe = alloc((size_t)BB * SS * DD);
  float* gxA = alloc(2ull * 2048ull * 2048ull);
  (void)ws_size; (void)in_sizes; (void)n_in; (void)out_size;

  hipMemsetAsync(d_ws, 0, state_n * sizeof(float), stream);

  // fp16 weight conversion (parallel, independent)
  f2h_k<<<(4096 * 1536 / 8 + 255) / 256, 256, 0, stream>>>(dwih0, w16i0, 4096 * 1536 / 8);
  f2h_k<<<(4096 * 1024 / 8 + 255) / 256, 256, 0, stream>>>(dwhh0, w16h0, 4096 * 1024 / 8);
  f2h_k<<<(4096 * 1024 / 8 + 255) / 256, 256, 0, stream>>>(dwih1, w16i1, 4096 * 1024 / 8);
  f2h_k<<<(4096 * 1024 / 8 + 255) / 256, 256, 0, stream>>>(dwhh1, w16h1, 4096 * 1024 / 8);
  f2h_k<<<(1024 * 2048 / 8 + 255) / 256, 256, 0, stream>>>(attn_w, aw16, 1024 * 2048 / 8);
  f2h_k<<<(VO * DD / 8 + 255) / 256, 256, 0, stream>>>(out_w, ow16, VO * DD / 8);

  gather_k<<<dim3(SS, BB), 128, 0, stream>>>(x, in_emb, xs_emb, SS);
  gather_k<<<dim3(TT, BB), 128, 0, stream>>>(gs, out_emb, gs_emb, TT);

  // encoder layer 0: parallel x-part (W L1-resident), then persistent recurrence
  gemv16c_k<EE><<<dim3(512, 2), 256, 0, stream>>>(
      xs_emb, EE, ewih0, EE, gxA, 2048, (size_t)4 * HH * EE, 2048ull * 2048ull);
  enc_mega7_k<<<256, 512, 0, stream>>>(gxA, ewhh0, eb0, ehA, l0, BB * 2 * HH, 2 * HH, bar);
  // encoder layer 1
  gemv16c_k<2 * HH><<<dim3(512, 2), 256, 0, stream>>>(
      l0, 2 * HH, ewih1, 2 * HH, gxA, 2048, (size_t)4 * HH * 2 * HH, 2048ull * 2048ull);
  enc_mega7_k<<<256, 512, 0, stream>>>(gxA, ewhh1, eb1, ehB, enc_out, 2 * HH, SS * 2 * HH,
                                       bar + 2 * 16384);
  // step-invariant attention term (fp32)
  encwe2_k<<<dim3(128, 16), 512, 0, stream>>>(enc_out, attn_w, encWe);

  // persistent decoder (R12 proven structure, fp16 weight streams)
  dec_mega7h_k<<<256, 1024, 0, stream>>>(gs_emb, encWe, enc_out, aw16, attn_b, attn_v,
                                         w16i0, w16h0, db0, w16i1, w16h1, db1, zeros,
                                         h0_all, h1_all, c1_all, wtd_all, qW_all,
                                         scores_all, bar + 4 * 16384);

  // all logits (h1 slots 1..128), fp16 out_w
  logits2h_k<<<dim3(TT, 125), 1024, 0, stream>>>(h1_all + BB * DD, ow16, out_b, out);
}